// Round 8
// baseline (31.764 us; speedup 1.0000x reference)
//
#include <hip/hip_runtime.h>

// EquivariantMultiheadAttention — B=4, N=128, S=8, CIN=COUT=8, GDIM=7
//
// Softmax over key dims (j,s2) cancels the query factor exp(y_i*w_y1) and the
// biases exp(b_g+b_y) exactly:
//   out[b,i,s1,c] = ( y[b,i,s1,c] + num/den ) * mask[b,i,s1], then @ w_lin^T
//   num = sum_{j,s2} exp(g.wg[c]) * kw * y[b,j,s2,c]
//   den = sum_{j,s2} exp(g.wg[c]) * kw,   kw = mask[b,j,s2] ? exp(y*w_y[c,0]) : 0
//
// R8 = R7 + depth-2 counted-vmcnt pipeline (T4). R7 drained vmcnt(0) per
// group -> ~300-500cy memory-idle bubble per group per wave. Here each wave
// stages group g+2 into a double-buffered LDS payload BEFORE computing group
// g and waits vmcnt(9) (9 = 7 stage loads + 2 y/mask loads of group g+1 stay
// in flight) -> outstanding loads never drop below 9 per wave; the CU memory
// pipe never idles. LDS 136 KB -> 1 block/CU; grid 512 = 2 sequential blocks
// per CU (dispatch stagger covers tails). Main loop fully unrolled so all
// buffer/register indices are static.

namespace {

constexpr int kC = 8, kO = 8, kG = 7;

typedef const __attribute__((address_space(1))) unsigned int* gp_t;
typedef __attribute__((address_space(3))) unsigned int* lp_t;

__device__ __forceinline__ float sgpr_pin(float x) {
    return __int_as_float(__builtin_amdgcn_readfirstlane(__float_as_int(x)));
}

// LDS arena (floats):
//   [0, 28672)        payload: wave w at w*3584, two buffers of 1792
//   [28672, 30848)    kwT: wave w at +w*272 (4 j rows, stride 68)
//   [30848, 33024)    kvT: wave w at +w*272
//   [33024, 34048)    red[8][8][16]
//   [34048, 34112)    obuf[8][8]
// total 136448 B -> 1 block/CU.

__global__ __launch_bounds__(512, 2)
void emha_kernel(const float* __restrict__ pg,     // (B,N,N,S,S,G)
                 const float* __restrict__ y,      // (B,N,S,C)
                 const int*   __restrict__ mask,   // (B,N,S) 0/1
                 const float* __restrict__ w_y,    // (C,2)
                 const float* __restrict__ w_g,    // (C,G)
                 const float* __restrict__ w_lin,  // (O,C)
                 float*       __restrict__ out)    // (B,N,S,O)
{
    __shared__ __align__(16) float arena[34112];

    const int t  = threadIdx.x;              // 0..511
    const int w  = t >> 6;                   // wave 0..7
    const int l  = t & 63;
    const int bi = blockIdx.x;               // b*N + i
    const int b  = bi >> 7;
    const int i  = bi & 127;

    float* pay0 = arena + w * 3584;
    float* pay1 = pay0 + 1792;
    float* kwT  = arena + 28672 + w * 272;
    float* kvT  = arena + 30848 + w * 272;
    float* red  = arena + 33024;             // [8][8][16]
    float* obuf = arena + 34048;             // [8][8]

    const float* slab = pg + (size_t)bi * 57344;
    const float* yb   = y    + b * 8192;
    const int*   mb   = mask + b * 1024;

    // SGPR-pinned weights
    float wy0[kC];
#pragma unroll
    for (int c = 0; c < kC; ++c) wy0[c] = sgpr_pin(w_y[2 * c]);
    float wg[kC][kG];
#pragma unroll
    for (int c = 0; c < kC; ++c)
#pragma unroll
        for (int g = 0; g < kG; ++g) wg[c][g] = sgpr_pin(w_g[c * kG + g]);

    // lane roles
    const int w16 = l & 15;                  // table-build slot
    const int jy  = l >> 4;                  // j offset within group
    const int s2y = w16 >> 1;                // table-build s2
    const int cb  = (w16 & 1) * 4;           // table-build c base
    const int jl  = l >> 4;                  // consume: local j
    const int h   = l & 1;                   // consume: s2 half

    // staging: 32 pairs * 224B contiguous -> 7 x 1KB global_load_lds
    auto stage = [&](int g) {
        const float* src = slab + (size_t)(w * 128 + g * 32) * 56 + l * 4;
        float* dst = (g & 1) ? pay1 : pay0;
#pragma unroll
        for (int q = 0; q < 7; ++q)
            __builtin_amdgcn_global_load_lds((gp_t)(src + q * 256),
                                             (lp_t)(dst + q * 256), 16, 0, 0);
    };

    float4 yvs[4]; int mvs[4];               // static-indexed after unroll
    auto loady = [&](int g) {
        const int jg = 16 * w + 4 * g + jy;
        yvs[g] = *reinterpret_cast<const float4*>(yb + jg * 64 + w16 * 4);
        mvs[g] = mb[jg * 8 + s2y];
    };

    // ---- prologue: two groups in flight (order matters for vmcnt math) ----
    stage(0); loady(0);                      // 7 + 2
    stage(1); loady(1);                      // 7 + 2  -> 18 outstanding

    float num[kC], den[kC];
#pragma unroll
    for (int c = 0; c < kC; ++c) { num[c] = 0.0f; den[c] = 0.0f; }

#pragma unroll
    for (int g = 0; g < 4; ++g) {
        // wait for group g only: leave group g+1's 9 loads in flight
        if (g < 3) { asm volatile("s_waitcnt vmcnt(9)" ::: "memory"); }
        else       { asm volatile("s_waitcnt vmcnt(0)" ::: "memory"); }
        __builtin_amdgcn_sched_barrier(0);

        // build this group's kw/kv table rows (4 slots per lane)
        {
            const float yv4[4] = {yvs[g].x, yvs[g].y, yvs[g].z, yvs[g].w};
            float kwq[4], kvq[4];
#pragma unroll
            for (int k = 0; k < 4; ++k) {
                const float e = __expf(yv4[k] * wy0[cb + k]);
                kwq[k] = mvs[g] ? e : 0.0f;
                kvq[k] = kwq[k] * yv4[k];
            }
            const int toff = jy * 68 + w16 * 4;
            *reinterpret_cast<float4*>(kwT + toff) =
                make_float4(kwq[0], kwq[1], kwq[2], kwq[3]);
            *reinterpret_cast<float4*>(kvT + toff) =
                make_float4(kvq[0], kvq[1], kvq[2], kvq[3]);
        }

        // payload -> registers (7 x ds_read_b128)
        float4 pv[7];
        {
            const float* pb = ((g & 1) ? pay1 : pay0) + l * 28;
            const float4* ps = reinterpret_cast<const float4*>(pb);
#pragma unroll
            for (int q = 0; q < 7; ++q) pv[q] = ps[q];
        }
        // drain LDS ops, then refill the pipeline two groups ahead
        asm volatile("s_waitcnt lgkmcnt(0)" ::: "memory");
        __builtin_amdgcn_sched_barrier(0);
        if (g < 2) { stage(g + 2); loady(g + 2); }
        __builtin_amdgcn_sched_barrier(0);

        // register-only compute (hides the in-flight loads)
        const float* pf = reinterpret_cast<const float*>(pv);
#pragma unroll
        for (int s2i = 0; s2i < 4; ++s2i) {
            const int ro = jl * 68 + (h * 4 + s2i) * 8;
            const float4 kwa = *reinterpret_cast<const float4*>(kwT + ro);
            const float4 kwb = *reinterpret_cast<const float4*>(kwT + ro + 4);
            const float4 kva = *reinterpret_cast<const float4*>(kvT + ro);
            const float4 kvb = *reinterpret_cast<const float4*>(kvT + ro + 4);
            const float kwv[8] = {kwa.x, kwa.y, kwa.z, kwa.w,
                                  kwb.x, kwb.y, kwb.z, kwb.w};
            const float kvv[8] = {kva.x, kva.y, kva.z, kva.w,
                                  kvb.x, kvb.y, kvb.z, kvb.w};
#pragma unroll
            for (int c = 0; c < kC; ++c) {
                float d =      pf[s2i * kG + 0] * wg[c][0];
                d = fmaf(pf[s2i * kG + 1], wg[c][1], d);
                d = fmaf(pf[s2i * kG + 2], wg[c][2], d);
                d = fmaf(pf[s2i * kG + 3], wg[c][3], d);
                d = fmaf(pf[s2i * kG + 4], wg[c][4], d);
                d = fmaf(pf[s2i * kG + 5], wg[c][5], d);
                d = fmaf(pf[s2i * kG + 6], wg[c][6], d);
                const float e = __expf(d);
                num[c] = fmaf(e, kvv[c], num[c]);
                den[c] = fmaf(e, kwv[c], den[c]);
            }
        }
    }

    // ---- reduce lanes sharing s1 = (l>>1)&7 (free bits: 0=h, 4,5=jl) ----
#pragma unroll
    for (int c = 0; c < kC; ++c) {
        num[c] += __shfl_xor(num[c], 1);
        num[c] += __shfl_xor(num[c], 16);
        num[c] += __shfl_xor(num[c], 32);
        den[c] += __shfl_xor(den[c], 1);
        den[c] += __shfl_xor(den[c], 16);
        den[c] += __shfl_xor(den[c], 32);
    }
    if (l < 16 && (l & 1) == 0) {
        const int s1 = l >> 1;
#pragma unroll
        for (int c = 0; c < kC; ++c) {
            red[w * 128 + s1 * 16 + c]     = num[c];
            red[w * 128 + s1 * 16 + 8 + c] = den[c];
        }
    }
    __syncthreads();

    // ---- cross-wave reduce + residual + query mask ----
    if (t < 64) {
        const int s1q = t >> 3, cc = t & 7;
        float ns = 0.0f, ds = 0.0f;
#pragma unroll
        for (int ww = 0; ww < 8; ++ww) {
            ns += red[ww * 128 + s1q * 16 + cc];
            ds += red[ww * 128 + s1q * 16 + 8 + cc];
        }
        const float yvq = yb[(i * 8 + s1q) * 8 + cc];
        const int   mq  = mb[i * 8 + s1q];
        obuf[s1q * 8 + cc] = mq ? (yvq + ns / ds) : 0.0f;
    }
    __syncthreads();

    // ---- output linear (c -> o), coalesced 64-float store ----
    if (t < 64) {
        const int s1q = t >> 3, o = t & 7;
        float acc = 0.0f;
#pragma unroll
        for (int c = 0; c < kC; ++c)
            acc = fmaf(obuf[s1q * 8 + c], w_lin[o * kC + c], acc);
        out[(size_t)bi * 64 + t] = acc;
    }
}

} // namespace

extern "C" void kernel_launch(void* const* d_in, const int* in_sizes, int n_in,
                              void* d_out, int out_size, void* d_ws, size_t ws_size,
                              hipStream_t stream)
{
    const float* pg    = (const float*)d_in[0];  // pairwise_g
    const float* y     = (const float*)d_in[1];  // coset_functions
    const int*   mask  = (const int*)  d_in[2];  // mask (bool -> int32)
    const float* w_y   = (const float*)d_in[3];
    // d_in[4] = b_y, d_in[6] = b_g: cancel in the softmax -> unused
    const float* w_g   = (const float*)d_in[5];
    const float* w_lin = (const float*)d_in[7];
    float* out = (float*)d_out;

    emha_kernel<<<512, 512, 0, stream>>>(pg, y, mask, w_y, w_g, w_lin, out);
}

// Round 9
// 28.064 us; speedup vs baseline: 1.1318x; 1.1318x over previous
//
#include <hip/hip_runtime.h>

// EquivariantMultiheadAttention — B=4, N=128, S=8, CIN=COUT=8, GDIM=7
//
// Softmax over key dims (j,s2) cancels the query factor exp(y_i*w_y1) and the
// biases exp(b_g+b_y) exactly:
//   out[b,i,s1,c] = ( y[b,i,s1,c] + num/den ) * mask[b,i,s1], then @ w_lin^T
//   num = sum_{j,s2} exp(g.wg[c]) * kw * y[b,j,s2,c]
//   den = sum_{j,s2} exp(g.wg[c]) * kw,   kw = mask[b,j,s2] ? exp(y*w_y[c,0]) : 0
//
// R9 = R7's occupancy (2 blocks/CU, 8 waves/CU) + R8's depth-2 counted-vmcnt
// pipeline, WITHOUT the LDS blowup: 256-thread blocks (4 waves), each wave
// owns 32 j-rows as 8 groups of 32 pairs, double-buffered 7KB payload.
// Set = {7 global_load_lds + float4 y + mask} = 9 vmem ops, sets issued in
// strict order; at group-g top, vmcnt(9) drains exactly set g, leaving set
// g+1 (and soon g+2) in flight -> per-wave outstanding never drops below
// 9 ops (~7KB); CU-aggregate ~56KB >> the ~22KB needed to cover HBM latency.
// Per-wave in-order DS makes table reuse safe; lgkmcnt(0) before re-staging
// protects the payload buffer; sched_barrier(0) pins the counted regions.

namespace {

constexpr int kC = 8, kO = 8, kG = 7;

typedef const __attribute__((address_space(1))) unsigned int* gp_t;
typedef __attribute__((address_space(3))) unsigned int* lp_t;

__device__ __forceinline__ float sgpr_pin(float x) {
    return __int_as_float(__builtin_amdgcn_readfirstlane(__float_as_int(x)));
}

// LDS arena (floats):
//   [0, 14336)        payload: wave w at w*3584, buffers at +0 / +1792
//   [14336, 15424)    kwT: wave w at +w*272 (4 j rows, stride 68)
//   [15424, 16512)    kvT: wave w at +w*272
//   [16512, 17024)    red[4][8][16]
//   [17024, 17088)    obuf[8][8]
// total 68352 B -> 2 blocks/CU.

__global__ __launch_bounds__(256, 2)
void emha_kernel(const float* __restrict__ pg,     // (B,N,N,S,S,G)
                 const float* __restrict__ y,      // (B,N,S,C)
                 const int*   __restrict__ mask,   // (B,N,S) 0/1
                 const float* __restrict__ w_y,    // (C,2)
                 const float* __restrict__ w_g,    // (C,G)
                 const float* __restrict__ w_lin,  // (O,C)
                 float*       __restrict__ out)    // (B,N,S,O)
{
    __shared__ __align__(16) float arena[17088];

    const int t  = threadIdx.x;              // 0..255
    const int w  = t >> 6;                   // wave 0..3
    const int l  = t & 63;
    const int bi = blockIdx.x;               // b*N + i
    const int b  = bi >> 7;
    const int i  = bi & 127;

    float* pay0 = arena + w * 3584;
    float* pay1 = pay0 + 1792;
    float* kwT  = arena + 14336 + w * 272;
    float* kvT  = arena + 15424 + w * 272;
    float* red  = arena + 16512;             // [4][8][16]
    float* obuf = arena + 17024;             // [8][8]

    const float* slab = pg + (size_t)bi * 57344;
    const float* yb   = y    + b * 8192;
    const int*   mb   = mask + b * 1024;

    // SGPR-pinned weights
    float wy0[kC];
#pragma unroll
    for (int c = 0; c < kC; ++c) wy0[c] = sgpr_pin(w_y[2 * c]);
    float wg[kC][kG];
#pragma unroll
    for (int c = 0; c < kC; ++c)
#pragma unroll
        for (int g = 0; g < kG; ++g) wg[c][g] = sgpr_pin(w_g[c * kG + g]);

    // lane roles
    const int w16 = l & 15;                  // table-build slot
    const int jy  = l >> 4;                  // table-build j offset in group
    const int s2y = w16 >> 1;                // table-build s2
    const int cb  = (w16 & 1) * 4;           // table-build c base
    const int jl  = l >> 4;                  // consume: local j (pair m>>3)
    const int h   = l & 1;                   // consume: s2 half

    // staging: 32 pairs * 224B = 7KB contiguous -> 7 x 1KB global_load_lds.
    // wave w group g covers pairs [256w + 32g, +32)  (j = 32w+4g+jl).
    auto stage = [&](int g) {
        const float* src = slab + (size_t)(256 * w + 32 * g) * 56 + l * 4;
        float* dst = (g & 1) ? pay1 : pay0;
#pragma unroll
        for (int q = 0; q < 7; ++q)
            __builtin_amdgcn_global_load_lds((gp_t)(src + q * 256),
                                             (lp_t)(dst + q * 256), 16, 0, 0);
    };

    float4 yvs[2]; int mvs[2];               // static-indexed (full unroll)
    auto loady = [&](int g) {
        const int jg = 32 * w + 4 * g + jy;
        yvs[g & 1] = *reinterpret_cast<const float4*>(yb + jg * 64 + w16 * 4);
        mvs[g & 1] = mb[jg * 8 + s2y];
    };

    // ---- prologue: two sets in flight (set = 7 stages + 2 y/mask = 9) ----
    stage(0); loady(0);
    stage(1); loady(1);
    __builtin_amdgcn_sched_barrier(0);

    float num[kC], den[kC];
#pragma unroll
    for (int c = 0; c < kC; ++c) { num[c] = 0.0f; den[c] = 0.0f; }

#pragma unroll
    for (int g = 0; g < 8; ++g) {
        // drain exactly set g (oldest 9): leaves set g+1 (+ g+2 soon) in flight
        if (g < 7) { asm volatile("s_waitcnt vmcnt(9)" ::: "memory"); }
        else       { asm volatile("s_waitcnt vmcnt(0)" ::: "memory"); }
        __builtin_amdgcn_sched_barrier(0);

        // build this group's 4 kw/kv table rows (4 slots per lane)
        {
            const float4 yq = yvs[g & 1];
            const int    mq = mvs[g & 1];
            const float yv4[4] = {yq.x, yq.y, yq.z, yq.w};
            float kwq[4], kvq[4];
#pragma unroll
            for (int k = 0; k < 4; ++k) {
                const float e = __expf(yv4[k] * wy0[cb + k]);
                kwq[k] = mq ? e : 0.0f;
                kvq[k] = kwq[k] * yv4[k];
            }
            const int toff = jy * 68 + w16 * 4;
            *reinterpret_cast<float4*>(kwT + toff) =
                make_float4(kwq[0], kwq[1], kwq[2], kwq[3]);
            *reinterpret_cast<float4*>(kvT + toff) =
                make_float4(kvq[0], kvq[1], kvq[2], kvq[3]);
        }

        // payload -> registers (7 x ds_read_b128)
        float4 pv[7];
        {
            const float* pb = ((g & 1) ? pay1 : pay0) + l * 28;
            const float4* ps = reinterpret_cast<const float4*>(pb);
#pragma unroll
            for (int q = 0; q < 7; ++q) pv[q] = ps[q];
        }
        // drain DS (payload now in regs, table writes landed), then refill
        // the pipeline two groups ahead into the just-freed buffer.
        asm volatile("s_waitcnt lgkmcnt(0)" ::: "memory");
        __builtin_amdgcn_sched_barrier(0);
        if (g < 6) { stage(g + 2); loady(g + 2); }
        __builtin_amdgcn_sched_barrier(0);

        // register-only compute (in-flight loads proceed underneath)
        const float* pf = reinterpret_cast<const float*>(pv);
#pragma unroll
        for (int s2i = 0; s2i < 4; ++s2i) {
            const int ro = jl * 68 + (h * 4 + s2i) * 8;
            const float4 kwa = *reinterpret_cast<const float4*>(kwT + ro);
            const float4 kwb = *reinterpret_cast<const float4*>(kwT + ro + 4);
            const float4 kva = *reinterpret_cast<const float4*>(kvT + ro);
            const float4 kvb = *reinterpret_cast<const float4*>(kvT + ro + 4);
            const float kwv[8] = {kwa.x, kwa.y, kwa.z, kwa.w,
                                  kwb.x, kwb.y, kwb.z, kwb.w};
            const float kvv[8] = {kva.x, kva.y, kva.z, kva.w,
                                  kvb.x, kvb.y, kvb.z, kvb.w};
#pragma unroll
            for (int c = 0; c < kC; ++c) {
                float d =      pf[s2i * kG + 0] * wg[c][0];
                d = fmaf(pf[s2i * kG + 1], wg[c][1], d);
                d = fmaf(pf[s2i * kG + 2], wg[c][2], d);
                d = fmaf(pf[s2i * kG + 3], wg[c][3], d);
                d = fmaf(pf[s2i * kG + 4], wg[c][4], d);
                d = fmaf(pf[s2i * kG + 5], wg[c][5], d);
                d = fmaf(pf[s2i * kG + 6], wg[c][6], d);
                const float e = __expf(d);
                num[c] = fmaf(e, kvv[c], num[c]);
                den[c] = fmaf(e, kwv[c], den[c]);
            }
        }
    }

    // ---- reduce lanes sharing s1 = (l>>1)&7 (free bits: 0=h, 4,5=jl) ----
#pragma unroll
    for (int c = 0; c < kC; ++c) {
        num[c] += __shfl_xor(num[c], 1);
        num[c] += __shfl_xor(num[c], 16);
        num[c] += __shfl_xor(num[c], 32);
        den[c] += __shfl_xor(den[c], 1);
        den[c] += __shfl_xor(den[c], 16);
        den[c] += __shfl_xor(den[c], 32);
    }
    if (l < 16 && (l & 1) == 0) {
        const int s1 = l >> 1;
#pragma unroll
        for (int c = 0; c < kC; ++c) {
            red[w * 128 + s1 * 16 + c]     = num[c];
            red[w * 128 + s1 * 16 + 8 + c] = den[c];
        }
    }
    __syncthreads();

    // ---- cross-wave reduce + residual + query mask ----
    if (t < 64) {
        const int s1q = t >> 3, cc = t & 7;
        float ns = 0.0f, ds = 0.0f;
#pragma unroll
        for (int ww = 0; ww < 4; ++ww) {
            ns += red[ww * 128 + s1q * 16 + cc];
            ds += red[ww * 128 + s1q * 16 + 8 + cc];
        }
        const float yvq = yb[(i * 8 + s1q) * 8 + cc];
        const int   mq  = mb[i * 8 + s1q];
        obuf[s1q * 8 + cc] = mq ? (yvq + ns / ds) : 0.0f;
    }
    __syncthreads();

    // ---- output linear (c -> o), coalesced 64-float store ----
    if (t < 64) {
        const int s1q = t >> 3, o = t & 7;
        float acc = 0.0f;
#pragma unroll
        for (int c = 0; c < kC; ++c)
            acc = fmaf(obuf[s1q * 8 + c], w_lin[o * kC + c], acc);
        out[(size_t)bi * 64 + t] = acc;
    }
}

} // namespace

extern "C" void kernel_launch(void* const* d_in, const int* in_sizes, int n_in,
                              void* d_out, int out_size, void* d_ws, size_t ws_size,
                              hipStream_t stream)
{
    const float* pg    = (const float*)d_in[0];  // pairwise_g
    const float* y     = (const float*)d_in[1];  // coset_functions
    const int*   mask  = (const int*)  d_in[2];  // mask (bool -> int32)
    const float* w_y   = (const float*)d_in[3];
    // d_in[4] = b_y, d_in[6] = b_g: cancel in the softmax -> unused
    const float* w_g   = (const float*)d_in[5];
    const float* w_lin = (const float*)d_in[7];
    float* out = (float*)d_out;

    emha_kernel<<<512, 256, 0, stream>>>(pg, y, mask, w_y, w_g, w_lin, out);
}

// Round 10
// 26.965 us; speedup vs baseline: 1.1780x; 1.0408x over previous
//
#include <hip/hip_runtime.h>

// EquivariantMultiheadAttention — B=4, N=128, S=8, CIN=COUT=8, GDIM=7
//
// FINAL (R10 = R7 revert, best of 9 structures at 26.88 µs).
//
// Softmax over key dims (j,s2) cancels the query factor exp(y_i*w_y1) and the
// biases exp(b_g+b_y) exactly:
//   out[b,i,s1,c] = ( y[b,i,s1,c] + num/den ) * mask[b,i,s1], then @ w_lin^T
//   num = sum_{j,s2} exp(g.wg[c]) * kw * y[b,j,s2,c]
//   den = sum_{j,s2} exp(g.wg[c]) * kw,   kw = mask[b,j,s2] ? exp(y*w_y[c,0]) : 0
//
// Structure: fully-coalesced loads + wave-autonomous depth-1 pipeline.
// 8 waves/block, one block per (b,i); each wave owns 16 j-rows (4 groups x
// 32 pairs), stages the contiguous 7 KB group payload via global_load_lds
// (1 KB/instr), builds its private kw/kv table from one coalesced float4
// y-load, computes from registers. No main-loop barriers. 2 blocks/CU.
//
// Ceiling evidence (R1-R9): nine schedules (occupancy 2-16 waves/CU, strided
// vs coalesced, pipeline depth 0/1/2, 1-2 kernels) all land 26.9-33 µs;
// 117.4 MB / 26.9 µs = 4.4 TB/s = the L3-resident read-path ceiling (input
// fits Infinity Cache across graph replays; HBM write ceiling of the fill
// kernels, 7.2 TB/s, does not apply to L3-hit reads).

namespace {

constexpr int kC = 8, kO = 8, kG = 7;

typedef const __attribute__((address_space(1))) unsigned int* gp_t;
typedef __attribute__((address_space(3))) unsigned int* lp_t;

__device__ __forceinline__ float sgpr_pin(float x) {
    return __int_as_float(__builtin_amdgcn_readfirstlane(__float_as_int(x)));
}

// LDS arena (floats):
//   [0, 14336)        payload: wave w at w*1792 (32 pairs * 56 floats)
//   [14336, 16512)    kwT: wave w at +w*272 (4 j rows, stride 68)
//   [16512, 18688)    kvT: wave w at +w*272
//   [18688, 19712)    red[8][8][16]
//   [19712, 19776)    obuf[8][8]
// total 79104 B -> 2 blocks/CU.

__global__ __launch_bounds__(512, 4)
void emha_kernel(const float* __restrict__ pg,     // (B,N,N,S,S,G)
                 const float* __restrict__ y,      // (B,N,S,C)
                 const int*   __restrict__ mask,   // (B,N,S) 0/1
                 const float* __restrict__ w_y,    // (C,2)
                 const float* __restrict__ w_g,    // (C,G)
                 const float* __restrict__ w_lin,  // (O,C)
                 float*       __restrict__ out)    // (B,N,S,O)
{
    __shared__ __align__(16) float arena[19776];

    const int t  = threadIdx.x;              // 0..511
    const int w  = t >> 6;                   // wave 0..7
    const int l  = t & 63;
    const int bi = blockIdx.x;               // b*N + i
    const int b  = bi >> 7;
    const int i  = bi & 127;

    float* pay  = arena + w * 1792;
    float* kwT  = arena + 14336 + w * 272;
    float* kvT  = arena + 16512 + w * 272;
    float* red  = arena + 18688;             // [8][8][16]
    float* obuf = arena + 19712;             // [8][8]

    const float* slab = pg + (size_t)bi * 57344;
    const float* yb   = y    + b * 8192;
    const int*   mb   = mask + b * 1024;

    // SGPR-pinned weights (keeps VGPR under the (512,4) 128-reg cap)
    float wy0[kC];
#pragma unroll
    for (int c = 0; c < kC; ++c) wy0[c] = sgpr_pin(w_y[2 * c]);
    float wg[kC][kG];
#pragma unroll
    for (int c = 0; c < kC; ++c)
#pragma unroll
        for (int g = 0; g < kG; ++g) wg[c][g] = sgpr_pin(w_g[c * kG + g]);

    // lane roles
    const int w16 = l & 15;                  // table-build slot group
    const int jy  = l >> 4;                  // j offset within group (both maps)
    const int s2y = w16 >> 1;                // table-build s2
    const int cb  = (w16 & 1) * 4;           // table-build c base
    const int jl  = l >> 4;                  // consume: local j
    const int h   = l & 1;                   // consume: s2 half

    // ---- staging helpers (all unit-stride / coalesced) ----
    // payload: 32 pairs * 224B contiguous; dst = uniform base, HW adds lane*16
    auto stage = [&](int g) {
        const float* src = slab + (size_t)(w * 128 + g * 32) * 56 + l * 4;
#pragma unroll
        for (int q = 0; q < 7; ++q)
            __builtin_amdgcn_global_load_lds((gp_t)(src + q * 256),
                                             (lp_t)(pay + q * 256), 16, 0, 0);
    };

    float4 yv; int mv;
    auto loady = [&](int g) {
        const int jg = 16 * w + 4 * g + jy;
        yv = *reinterpret_cast<const float4*>(yb + jg * 64 + w16 * 4);
        mv = mb[jg * 8 + s2y];
    };

    // ---- prologue ----
    stage(0);
    loady(0);

    float num[kC], den[kC];
#pragma unroll
    for (int c = 0; c < kC; ++c) { num[c] = 0.0f; den[c] = 0.0f; }

#pragma unroll 1
    for (int g = 0; g < 4; ++g) {
        // group g payload in LDS + y/mask in regs
        asm volatile("s_waitcnt vmcnt(0)" ::: "memory");
        __builtin_amdgcn_sched_barrier(0);

        // build this group's kw/kv table rows (4 slots per lane)
        {
            const float yv4[4] = {yv.x, yv.y, yv.z, yv.w};
            float kwq[4], kvq[4];
#pragma unroll
            for (int k = 0; k < 4; ++k) {
                const float e = __expf(yv4[k] * wy0[cb + k]);
                kwq[k] = mv ? e : 0.0f;
                kvq[k] = kwq[k] * yv4[k];
            }
            const int toff = jy * 68 + w16 * 4;
            *reinterpret_cast<float4*>(kwT + toff) =
                make_float4(kwq[0], kwq[1], kwq[2], kwq[3]);
            *reinterpret_cast<float4*>(kvT + toff) =
                make_float4(kvq[0], kvq[1], kvq[2], kvq[3]);
        }

        // payload -> registers (7 x ds_read_b128)
        float4 pv[7];
        {
            const float4* ps = reinterpret_cast<const float4*>(pay + l * 28);
#pragma unroll
            for (int q = 0; q < 7; ++q) pv[q] = ps[q];
        }
        // drain payload reads + table writes, THEN issue next group's loads
        asm volatile("s_waitcnt lgkmcnt(0)" ::: "memory");
        __builtin_amdgcn_sched_barrier(0);
        if (g < 3) { stage(g + 1); loady(g + 1); }

        // register-only compute (hides the in-flight loads)
        const float* pf = reinterpret_cast<const float*>(pv);
#pragma unroll
        for (int s2i = 0; s2i < 4; ++s2i) {
            const int ro = jl * 68 + (h * 4 + s2i) * 8;
            const float4 kwa = *reinterpret_cast<const float4*>(kwT + ro);
            const float4 kwb = *reinterpret_cast<const float4*>(kwT + ro + 4);
            const float4 kva = *reinterpret_cast<const float4*>(kvT + ro);
            const float4 kvb = *reinterpret_cast<const float4*>(kvT + ro + 4);
            const float kwv[8] = {kwa.x, kwa.y, kwa.z, kwa.w,
                                  kwb.x, kwb.y, kwb.z, kwb.w};
            const float kvv[8] = {kva.x, kva.y, kva.z, kva.w,
                                  kvb.x, kvb.y, kvb.z, kvb.w};
#pragma unroll
            for (int c = 0; c < kC; ++c) {
                float d =      pf[s2i * kG + 0] * wg[c][0];
                d = fmaf(pf[s2i * kG + 1], wg[c][1], d);
                d = fmaf(pf[s2i * kG + 2], wg[c][2], d);
                d = fmaf(pf[s2i * kG + 3], wg[c][3], d);
                d = fmaf(pf[s2i * kG + 4], wg[c][4], d);
                d = fmaf(pf[s2i * kG + 5], wg[c][5], d);
                d = fmaf(pf[s2i * kG + 6], wg[c][6], d);
                const float e = __expf(d);
                num[c] = fmaf(e, kvv[c], num[c]);
                den[c] = fmaf(e, kwv[c], den[c]);
            }
        }
    }

    // ---- reduce lanes sharing s1 = (l>>1)&7 (free bits: 0=h, 4,5=jl) ----
#pragma unroll
    for (int c = 0; c < kC; ++c) {
        num[c] += __shfl_xor(num[c], 1);
        num[c] += __shfl_xor(num[c], 16);
        num[c] += __shfl_xor(num[c], 32);
        den[c] += __shfl_xor(den[c], 1);
        den[c] += __shfl_xor(den[c], 16);
        den[c] += __shfl_xor(den[c], 32);
    }
    if (l < 16 && (l & 1) == 0) {
        const int s1 = l >> 1;
#pragma unroll
        for (int c = 0; c < kC; ++c) {
            red[w * 128 + s1 * 16 + c]     = num[c];
            red[w * 128 + s1 * 16 + 8 + c] = den[c];
        }
    }
    __syncthreads();

    // ---- cross-wave reduce + residual + query mask ----
    if (t < 64) {
        const int s1q = t >> 3, cc = t & 7;
        float ns = 0.0f, ds = 0.0f;
#pragma unroll
        for (int ww = 0; ww < 8; ++ww) {
            ns += red[ww * 128 + s1q * 16 + cc];
            ds += red[ww * 128 + s1q * 16 + 8 + cc];
        }
        const float yvq = yb[(i * 8 + s1q) * 8 + cc];
        const int   mq  = mb[i * 8 + s1q];
        obuf[s1q * 8 + cc] = mq ? (yvq + ns / ds) : 0.0f;
    }
    __syncthreads();

    // ---- output linear (c -> o), coalesced 64-float store ----
    if (t < 64) {
        const int s1q = t >> 3, o = t & 7;
        float acc = 0.0f;
#pragma unroll
        for (int c = 0; c < kC; ++c)
            acc = fmaf(obuf[s1q * 8 + c], w_lin[o * kC + c], acc);
        out[(size_t)bi * 64 + t] = acc;
    }
}

} // namespace

extern "C" void kernel_launch(void* const* d_in, const int* in_sizes, int n_in,
                              void* d_out, int out_size, void* d_ws, size_t ws_size,
                              hipStream_t stream)
{
    const float* pg    = (const float*)d_in[0];  // pairwise_g
    const float* y     = (const float*)d_in[1];  // coset_functions
    const int*   mask  = (const int*)  d_in[2];  // mask (bool -> int32)
    const float* w_y   = (const float*)d_in[3];
    // d_in[4] = b_y, d_in[6] = b_g: cancel in the softmax -> unused
    const float* w_g   = (const float*)d_in[5];
    const float* w_lin = (const float*)d_in[7];
    float* out = (float*)d_out;

    emha_kernel<<<512, 512, 0, stream>>>(pg, y, mask, w_y, w_g, w_lin, out);
}